// Round 4
// baseline (467.331 us; speedup 1.0000x reference)
//
#include <hip/hip_runtime.h>
#include <math.h>

// Problem constants (from reference): B=128, T=200, V=10, F=256.
constexpr int NV  = 10;
constexpr int NF  = 256;
constexpr int NC  = NV * NV;   // 100 cells per graph
constexpr int GPB = 4;         // graphs per block = 1 per wave (wave64)

// Native clang vector: __builtin_nontemporal_* requires ext_vector_type.
typedef float v4f __attribute__((ext_vector_type(4)));

// ============================================================================
// v5: split the fused kernel into (1) per-graph math and (2) a pure stream.
// Rationale: fused block lifetime = 3.2us stream + ~1.5us latency-chained
// math tail (FW LDS round-trips + transcendentals). At 8 blocks/CU (wave-slot
// capped) that tail drains the memory pipe ~30% of the time -> 4.4 TB/s.
// A pure-stream kernel has copy-shaped lifetime -> should run at ~6.3 TB/s
// like the fill/copy ubenches. Math kernel is tiny (25,600 waves de-phase).
// ============================================================================

// ---- Kernel 1: graph math. Writes out_atten + Di (ws) + embsum (ws). ----
__global__ __launch_bounds__(256) void graph_math(
    const float* __restrict__ S,           // (BT, V, V)
    const float* __restrict__ mul,         // (V, V)
    const float* __restrict__ bias,        // (V, V)
    const float* __restrict__ means,       // (1, V)
    const float* __restrict__ stds,        // (1, V)
    const float* __restrict__ emb_in,      // (F, F) rows 0..9 used
    const float* __restrict__ emb_out,     // (F, F)
    const float* __restrict__ emb3,        // (V, V)
    const float* __restrict__ emb4,        // (V, V)
    float* __restrict__ out_atten,         // (BT, V, V)
    int*   __restrict__ Di_ws,             // (BT, V)
    float* __restrict__ es_ws,             // (V, F) embsum table
    int BT)
{
    __shared__ float s_mul[NC], s_bias[NC], s_emb3[NC], s_emb4[NC];
    __shared__ float s_means[NV], s_stds[NV];
    __shared__ float s_dist[GPB][NC];
    __shared__ int   s_si[GPB][NC];
    __shared__ int   s_ei[GPB][NC];

    const int tid   = threadIdx.x;
    const int wave  = tid >> 6;
    const int lane  = tid & 63;
    const int gbase = blockIdx.x * GPB;
    const int g     = gbase + wave;

    // Block 0 publishes the precombined embedding-sum table for kernel 2.
    if (blockIdx.x == 0) {
        for (int idx = tid; idx < NV * NF; idx += 256)
            es_ws[idx] = emb_in[idx] + emb_out[idx];
    }

    // ---- Table staging (block-wide) ----
    if (tid < NC) {
        s_mul[tid]  = mul[tid];
        s_bias[tid] = bias[tid];
        s_emb3[tid] = emb3[tid];
        s_emb4[tid] = emb4[tid];
    }
    if (tid >= 128 && tid < 128 + NV) {
        s_means[tid - 128] = means[tid - 128];
        s_stds[tid - 128]  = stds[tid - 128];
    }
    __syncthreads();

    if (g >= BT) return;

    const int c0 = lane;          // cells 0..63
    const int c1 = 64 + lane;     // cells 64..99 (lane < 36)
    const bool has1 = (lane < 36);
    const int i0 = c0 / NV, j0 = c0 % NV;
    const int i1 = c1 / NV, j1 = c1 % NV;
    const int g0 = g * NC;

    // Symmetrize S into s_dist (sym == initial dist)
    s_dist[wave][c0] = fminf(S[g0 + c0], S[g0 + j0 * NV + i0]);
    if (has1)
        s_dist[wave][c1] = fminf(S[g0 + c1], S[g0 + j1 * NV + i1]);

    // Degree buckets (lanes 0..9), read pre-FW dist (== sym); publish to ws
    if (lane < NV) {
        float d = 0.f;
        #pragma unroll
        for (int i = 0; i < NV; ++i) d += s_dist[wave][i * NV + lane];
        int di = (int)d;   // d in [0,10): trunc == astype(int32)
        Di_ws[g * NV + lane] = min(max(di, 0), NV - 1);
    }

    // GaussianLayer edge features -> registers (uses pre-FW dist)
    const float A = sqrtf(2.0f * 3.14159f);
    float ef0 = 0.f, ef1 = 0.f, sp0 = 0.f, sp1 = 0.f;
    {
        float acc = 0.f;
        #pragma unroll
        for (int j = 0; j < NV; ++j)
            acc += s_dist[wave][i0 * NV + j] * s_mul[j * NV + j0];
        float x = acc + s_bias[c0];
        float z = (x - s_means[j0]) / s_stds[j0];
        float tmp = expf(-0.5f * z * z) / (A * s_stds[j0]);
        float sg = 1.0f / (1.0f + expf(-tmp));
        ef0 = tanhf(sg);
    }
    if (has1) {
        float acc = 0.f;
        #pragma unroll
        for (int j = 0; j < NV; ++j)
            acc += s_dist[wave][i1 * NV + j] * s_mul[j * NV + j1];
        float x = acc + s_bias[c1];
        float z = (x - s_means[j1]) / s_stds[j1];
        float tmp = expf(-0.5f * z * z) / (A * s_stds[j1]);
        float sg = 1.0f / (1.0f + expf(-tmp));
        ef1 = tanhf(sg);
    }

    // Floyd-Warshall, wave-synchronous, in-place. Safe intra-step: at step k,
    // reads touch only row-k/col-k cells, never relaxed at step k.
    #pragma unroll
    for (int k = 0; k < NV; ++k) {
        float t0 = s_dist[wave][i0 * NV + k] + s_dist[wave][k * NV + j0];
        if (t0 < s_dist[wave][c0]) { s_dist[wave][c0] = t0; sp0 += ef0; }
        if (has1) {
            float t1 = s_dist[wave][i1 * NV + k] + s_dist[wave][k * NV + j1];
            if (t1 < s_dist[wave][c1]) { s_dist[wave][c1] = t1; sp1 += ef1; }
        }
    }

    // Integer buckets
    {
        int si = (int)s_dist[wave][c0];
        int ei = (int)sp0;
        s_si[wave][c0] = min(max(si, 0), NV - 1);
        s_ei[wave][c0] = min(max(ei, 0), NV - 1);
    }
    if (has1) {
        int si = (int)s_dist[wave][c1];
        int ei = (int)sp1;
        s_si[wave][c1] = min(max(si, 0), NV - 1);
        s_ei[wave][c1] = min(max(ei, 0), NV - 1);
    }

    // atten_bias = sum_j emb3[Si[i,j]] + emb4[Ei[i,j]]  (per cell (i,cc))
    {
        float acc3 = 0.f, acc4 = 0.f;
        #pragma unroll
        for (int j = 0; j < NV; ++j) {
            acc3 += s_emb3[s_si[wave][i0 * NV + j] * NV + j0];
            acc4 += s_emb4[s_ei[wave][i0 * NV + j] * NV + j0];
        }
        __builtin_nontemporal_store(acc4 + acc3, out_atten + g0 + c0);
    }
    if (has1) {
        float acc3 = 0.f, acc4 = 0.f;
        #pragma unroll
        for (int j = 0; j < NV; ++j) {
            acc3 += s_emb3[s_si[wave][i1 * NV + j] * NV + j1];
            acc4 += s_emb4[s_ei[wave][i1 * NV + j] * NV + j1];
        }
        __builtin_nontemporal_store(acc4 + acc3, out_atten + g0 + c1);
    }
}

// ---- Kernel 2: pure stream. out_main = end_output + embsum[Di[g,row]] ----
__global__ __launch_bounds__(256) void stream_add(
    const float* __restrict__ end_output,  // (BT, V, F)
    const int*   __restrict__ Di_ws,       // (BT, V)
    const float* __restrict__ es_ws,       // (V, F)
    float* __restrict__ out_main,          // (BT, V, F)
    int BT)
{
    __shared__ __attribute__((aligned(16))) float s_es[NV * NF];
    __shared__ int s_di[GPB * NV];

    const int tid   = threadIdx.x;
    const int wave  = tid >> 6;
    const int lane  = tid & 63;
    const int gbase = blockIdx.x * GPB;

    // Stage embsum table (10 KB, L2-hot) + this block's 40 Di entries.
    {
        v4f* d4 = reinterpret_cast<v4f*>(s_es);
        const v4f* s4 = reinterpret_cast<const v4f*>(es_ws);
        for (int idx = tid; idx < NV * NF / 4; idx += 256)
            d4[idx] = s4[idx];
        const int ng = min(GPB, BT - gbase);
        if (tid < ng * NV) s_di[tid] = Di_ws[gbase * NV + tid];
    }
    __syncthreads();

    const size_t slab = (size_t)gbase * (NV * NF);
    const v4f* end4 = reinterpret_cast<const v4f*>(end_output + slab);
    v4f*       out4 = reinterpret_cast<v4f*>(out_main + slab);
    const v4f* es4  = reinterpret_cast<const v4f*>(s_es);

    if (gbase + GPB <= BT) {
        // Full block: 40 chunks of 64 float4; chunk == (g_local, V-row).
        // Fixed trip count, no division -> 10 independent nt dwordx4 loads
        // in flight per lane.
        #pragma unroll
        for (int it = 0; it < NV; ++it) {
            const int chunk = it * GPB + wave;
            const int u     = (chunk << 6) + lane;
            v4f e = __builtin_nontemporal_load(end4 + u);
            v4f s = es4[s_di[chunk] * (NF / 4) + lane];
            e += s;
            __builtin_nontemporal_store(e, out4 + u);
        }
    } else {
        const int ng    = BT - gbase;           // partial tail block
        const int items = ng * (NV * NF / 4);
        for (int u = tid; u < items; u += 256) {
            int gg = u / 640, rem = u - gg * 640;
            int row = rem >> 6, f4 = rem & 63;
            v4f e = __builtin_nontemporal_load(end4 + u);
            v4f s = es4[s_di[gg * NV + row] * (NF / 4) + f4];
            e += s;
            __builtin_nontemporal_store(e, out4 + u);
        }
    }
}

// ---- Fallback: v4 fused kernel (used only if workspace is too small) ----
__global__ __launch_bounds__(256) void graph_emb_fused(
    const float* __restrict__ end_output,
    const float* __restrict__ S,
    const float* __restrict__ mul,
    const float* __restrict__ bias,
    const float* __restrict__ means,
    const float* __restrict__ stds,
    const float* __restrict__ emb_in,
    const float* __restrict__ emb_out,
    const float* __restrict__ emb3,
    const float* __restrict__ emb4,
    float* __restrict__ out_main,
    float* __restrict__ out_atten,
    int BT)
{
    __shared__ __attribute__((aligned(16))) float s_embsum[NV * NF];
    __shared__ float s_mul[NC], s_bias[NC], s_emb3[NC], s_emb4[NC];
    __shared__ float s_means[NV], s_stds[NV];
    __shared__ float s_dist[GPB][NC];
    __shared__ int   s_si[GPB][NC];
    __shared__ int   s_ei[GPB][NC];
    __shared__ int   s_Di[GPB][NV];

    const int tid   = threadIdx.x;
    const int wave  = tid >> 6;
    const int lane  = tid & 63;
    const int gbase = blockIdx.x * GPB;
    const int g     = gbase + wave;

    for (int idx = tid; idx < NV * NF; idx += 256)
        s_embsum[idx] = emb_in[idx] + emb_out[idx];
    if (tid < NC) {
        s_mul[tid]  = mul[tid];
        s_bias[tid] = bias[tid];
        s_emb3[tid] = emb3[tid];
        s_emb4[tid] = emb4[tid];
    }
    if (tid >= 128 && tid < 128 + NV) {
        s_means[tid - 128] = means[tid - 128];
        s_stds[tid - 128]  = stds[tid - 128];
    }

    const int c0 = lane;
    const int c1 = 64 + lane;
    const bool has1 = (lane < 36);
    const int i0 = c0 / NV, j0 = c0 % NV;
    const int i1 = c1 / NV, j1 = c1 % NV;

    if (g < BT) {
        const int g0 = g * NC;
        s_dist[wave][c0] = fminf(S[g0 + c0], S[g0 + j0 * NV + i0]);
        if (has1)
            s_dist[wave][c1] = fminf(S[g0 + c1], S[g0 + j1 * NV + i1]);
        if (lane < NV) {
            float d = 0.f;
            #pragma unroll
            for (int i = 0; i < NV; ++i) d += s_dist[wave][i * NV + lane];
            int di = (int)d;
            s_Di[wave][lane] = min(max(di, 0), NV - 1);
        }
    }
    __syncthreads();

    {
        const size_t slab = (size_t)gbase * (NV * NF);
        const v4f* end4 = reinterpret_cast<const v4f*>(end_output + slab);
        v4f*       out4 = reinterpret_cast<v4f*>(out_main + slab);
        const v4f* es4  = reinterpret_cast<const v4f*>(s_embsum);
        const int* sdi  = &s_Di[0][0];

        if (gbase + GPB <= BT) {
            #pragma unroll
            for (int it = 0; it < NV; ++it) {
                const int chunk = it * GPB + wave;
                const int u     = (chunk << 6) + lane;
                v4f e = __builtin_nontemporal_load(end4 + u);
                v4f s = es4[sdi[chunk] * (NF / 4) + lane];
                e += s;
                __builtin_nontemporal_store(e, out4 + u);
            }
        } else {
            const int ng    = BT - gbase;
            const int items = ng * (NV * NF / 4);
            for (int u = tid; u < items; u += 256) {
                int gg = u / 640, rem = u - gg * 640;
                int row = rem >> 6, f4 = rem & 63;
                v4f e = __builtin_nontemporal_load(end4 + u);
                v4f s = es4[sdi[gg * NV + row] * (NF / 4) + f4];
                e += s;
                __builtin_nontemporal_store(e, out4 + u);
            }
        }
    }

    if (g < BT) {
        const int g0 = g * NC;
        const float A = sqrtf(2.0f * 3.14159f);
        float ef0 = 0.f, ef1 = 0.f, sp0 = 0.f, sp1 = 0.f;
        {
            float acc = 0.f;
            #pragma unroll
            for (int j = 0; j < NV; ++j)
                acc += s_dist[wave][i0 * NV + j] * s_mul[j * NV + j0];
            float x = acc + s_bias[c0];
            float z = (x - s_means[j0]) / s_stds[j0];
            float tmp = expf(-0.5f * z * z) / (A * s_stds[j0]);
            float sg = 1.0f / (1.0f + expf(-tmp));
            ef0 = tanhf(sg);
        }
        if (has1) {
            float acc = 0.f;
            #pragma unroll
            for (int j = 0; j < NV; ++j)
                acc += s_dist[wave][i1 * NV + j] * s_mul[j * NV + j1];
            float x = acc + s_bias[c1];
            float z = (x - s_means[j1]) / s_stds[j1];
            float tmp = expf(-0.5f * z * z) / (A * s_stds[j1]);
            float sg = 1.0f / (1.0f + expf(-tmp));
            ef1 = tanhf(sg);
        }
        #pragma unroll
        for (int k = 0; k < NV; ++k) {
            float t0 = s_dist[wave][i0 * NV + k] + s_dist[wave][k * NV + j0];
            if (t0 < s_dist[wave][c0]) { s_dist[wave][c0] = t0; sp0 += ef0; }
            if (has1) {
                float t1 = s_dist[wave][i1 * NV + k] + s_dist[wave][k * NV + j1];
                if (t1 < s_dist[wave][c1]) { s_dist[wave][c1] = t1; sp1 += ef1; }
            }
        }
        {
            int si = (int)s_dist[wave][c0];
            int ei = (int)sp0;
            s_si[wave][c0] = min(max(si, 0), NV - 1);
            s_ei[wave][c0] = min(max(ei, 0), NV - 1);
        }
        if (has1) {
            int si = (int)s_dist[wave][c1];
            int ei = (int)sp1;
            s_si[wave][c1] = min(max(si, 0), NV - 1);
            s_ei[wave][c1] = min(max(ei, 0), NV - 1);
        }
        {
            float acc3 = 0.f, acc4 = 0.f;
            #pragma unroll
            for (int j = 0; j < NV; ++j) {
                acc3 += s_emb3[s_si[wave][i0 * NV + j] * NV + j0];
                acc4 += s_emb4[s_ei[wave][i0 * NV + j] * NV + j0];
            }
            __builtin_nontemporal_store(acc4 + acc3, out_atten + g0 + c0);
        }
        if (has1) {
            float acc3 = 0.f, acc4 = 0.f;
            #pragma unroll
            for (int j = 0; j < NV; ++j) {
                acc3 += s_emb3[s_si[wave][i1 * NV + j] * NV + j1];
                acc4 += s_emb4[s_ei[wave][i1 * NV + j] * NV + j1];
            }
            __builtin_nontemporal_store(acc4 + acc3, out_atten + g0 + c1);
        }
    }
}

extern "C" void kernel_launch(void* const* d_in, const int* in_sizes, int n_in,
                              void* d_out, int out_size, void* d_ws, size_t ws_size,
                              hipStream_t stream) {
    const float* end_output = (const float*)d_in[0];
    const float* S          = (const float*)d_in[1];
    const float* mul        = (const float*)d_in[2];
    const float* bias       = (const float*)d_in[3];
    const float* means      = (const float*)d_in[4];
    const float* stds       = (const float*)d_in[5];
    const float* emb_in     = (const float*)d_in[6];
    const float* emb_out    = (const float*)d_in[7];
    const float* emb3       = (const float*)d_in[8];
    const float* emb4       = (const float*)d_in[9];

    float* out_main  = (float*)d_out;
    float* out_atten = out_main + (size_t)in_sizes[0];

    const int BT = in_sizes[1] / (NV * NV);         // 25,600
    const int nblocks = (BT + GPB - 1) / GPB;       // 6,400

    const size_t di_bytes = ((size_t)BT * NV * sizeof(int) + 15) & ~(size_t)15;
    const size_t need     = di_bytes + (size_t)NV * NF * sizeof(float);

    if (d_ws != nullptr && ws_size >= need) {
        int*   Di_ws = (int*)d_ws;
        float* es_ws = (float*)((char*)d_ws + di_bytes);
        graph_math<<<nblocks, 256, 0, stream>>>(
            S, mul, bias, means, stds, emb_in, emb_out, emb3, emb4,
            out_atten, Di_ws, es_ws, BT);
        stream_add<<<nblocks, 256, 0, stream>>>(
            end_output, Di_ws, es_ws, out_main, BT);
    } else {
        graph_emb_fused<<<nblocks, 256, 0, stream>>>(
            end_output, S, mul, bias, means, stds,
            emb_in, emb_out, emb3, emb4, out_main, out_atten, BT);
    }
}